// Round 3
// baseline (315.592 us; speedup 1.0000x reference)
//
#include <hip/hip_runtime.h>

// Problem: B=16,C=64,H=32,W=32 -> N=16384 tokens; K=8192 codes.
#define DECAYF 0.99f
#define OMDF   0.01f
#define TAU    6.0e-3f    // ambiguity margin; split-bf16 score err RMS ~3e-5 -> 100-sigma

typedef unsigned int u32;
typedef unsigned long long u64;
typedef __attribute__((ext_vector_type(8))) short bf16x8;   // 8 bf16 (4 VGPRs)
typedef __attribute__((ext_vector_type(16))) float f32x16;  // MFMA 32x32 acc

// ws layout (bytes)
#define EN_OFF     0              // en[8192] f32: 0.5*||e||^2
#define EFRAG_OFF  32768          // 4 MB frag-ordered bf16 hi/lo of emb
#define BEST1_OFF  4227072        // u64 [16384][4] per-(token,slice) best (enc)
#define BEST2_OFF  4751360        // f32 [16384][4] per-(token,slice) 2nd-best score
#define IDX_OFF    5013504        // i32 [16384] final indices
#define LIST_OFF   5079040        // i32 [16384] ambiguous-token list
#define CNT_OFF    5144576        // i32 count ; +4: f32 nsum

__device__ __forceinline__ u64 enc_pair(float s, int idx) {
  u32 u = __float_as_uint(s);
  u = (u & 0x80000000u) ? ~u : (u | 0x80000000u);   // order-preserving
  return ((u64)u << 32) | (u32)(~idx);              // ~idx: ties -> min idx
}
__device__ __forceinline__ float dec_score(u64 e) {
  u32 u = (u32)(e >> 32);
  u = (u & 0x80000000u) ? (u & 0x7fffffffu) : ~u;
  return __uint_as_float(u);
}
__device__ __forceinline__ int dec_idx(u64 e) { return (int)(~(u32)e); }
__device__ __forceinline__ unsigned short f2bf(float f) {  // f32 -> bf16 RNE
  u32 u = __float_as_uint(f);
  u += 0x7fffu + ((u >> 16) & 1u);
  return (unsigned short)(u >> 16);
}

// ---- fused: en = 0.5*||e||^2 (R1 bit-exact) + emb -> bf16 hi/lo frags ----
// frag layout: [tile32][kstep*2+split][h][n32][j]  (1024 B per kstep-split)
__global__ __launch_bounds__(256) void k_en_eprep(const float* __restrict__ emb,
                                                  float* __restrict__ en,
                                                  unsigned char* __restrict__ efrag) {
  int tid = blockIdx.x * 256 + threadIdx.x;   // 131072 float4s
  int k = tid >> 4, q = tid & 15;
  float4 v = ((const float4*)emb)[tid];
  // eprep part
  int kstep = q >> 2, h = (q >> 1) & 1, j0 = (q & 1) * 4;
  int tile = k >> 5, n32 = k & 31;
  ushort4 hi, lo;
  hi.x = f2bf(v.x); lo.x = f2bf(v.x - __uint_as_float((u32)hi.x << 16));
  hi.y = f2bf(v.y); lo.y = f2bf(v.y - __uint_as_float((u32)hi.y << 16));
  hi.z = f2bf(v.z); lo.z = f2bf(v.z - __uint_as_float((u32)hi.z << 16));
  hi.w = f2bf(v.w); lo.w = f2bf(v.w - __uint_as_float((u32)hi.w << 16));
  size_t off = (size_t)tile * 8192 + (size_t)(kstep * 2) * 1024
             + (size_t)h * 512 + (size_t)n32 * 16 + (size_t)j0 * 2;
  *(ushort4*)(efrag + off)        = hi;   // split 0 (hi)
  *(ushort4*)(efrag + off + 1024) = lo;   // split 1 (lo)
  // en part (identical chain to round 1)
  float s = v.x * v.x + v.y * v.y + v.z * v.z + v.w * v.w;
  s += __shfl_xor(s, 1, 16);
  s += __shfl_xor(s, 2, 16);
  s += __shfl_xor(s, 4, 16);
  s += __shfl_xor(s, 8, 16);
  if (q == 0) en[k] = 0.5f * s;
}

// ---- init EMA outputs ---------------------------------------------------
__global__ __launch_bounds__(256) void k_init(const float* __restrict__ cs_in,
                                              const float* __restrict__ avg_in,
                                              float* __restrict__ out4,
                                              float* __restrict__ out5) {
  int tid = blockIdx.x * 256 + threadIdx.x;
  if (tid < 131072) {
    float4 v = ((const float4*)avg_in)[tid];
    v.x *= DECAYF; v.y *= DECAYF; v.z *= DECAYF; v.w *= DECAYF;
    ((float4*)out5)[tid] = v;
  } else {
    int t = tid - 131072;
    float4 v = ((const float4*)cs_in)[t];
    v.x *= DECAYF; v.y *= DECAYF; v.z *= DECAYF; v.w *= DECAYF;
    ((float4*)out4)[t] = v;
  }
}

// ---- MFMA argmin: 32x32x16 bf16 split hi/lo, top-2 tracked per token -----
__global__ __launch_bounds__(256) void k_argmin_mfma(
    const float* __restrict__ z_e, const unsigned char* __restrict__ efrag,
    const float* __restrict__ en, u64* __restrict__ best1,
    float* __restrict__ best2) {
  alignas(16) __shared__ unsigned char sbuf[16384];   // 64 codes, frag order
  const int tb = blockIdx.x >> 2;            // token group (128 tokens)
  const int sl = blockIdx.x & 3;             // K-slice
  const int wave = threadIdx.x >> 6, lane = threadIdx.x & 63;
  const int h = lane >> 5, m = lane & 31;
  const int token0 = tb * 128 + wave * 32;

  bf16x8 ahi[4], alo[4];
  {
    const int token = token0 + m;
    const float* zp = z_e + ((size_t)(token >> 10) << 16) + (token & 1023);
#pragma unroll
    for (int ks = 0; ks < 4; ++ks) {
#pragma unroll
      for (int j = 0; j < 8; ++j) {
        int c = ks * 16 + h * 8 + j;
        float x = zp[(size_t)c << 10];
        unsigned short xh = f2bf(x);
        ahi[ks][j] = (short)xh;
        alo[ks][j] = (short)f2bf(x - __uint_as_float((u32)xh << 16));
      }
    }
  }
  float b1[16], i1[16], b2[16];
#pragma unroll
  for (int r = 0; r < 16; ++r) { b1[r] = -3.0e38f; b2[r] = -3.0e38f; i1[r] = 0.f; }

  const int scb = sl * 2048;
  const unsigned char* gbase0 = efrag + (size_t)scb * 256;   // 256 B/code
  for (int ib = 0; ib < 32; ++ib) {
    const unsigned char* g = gbase0 + (size_t)ib * 16384 + (size_t)wave * 4096;
#pragma unroll
    for (int it = 0; it < 4; ++it) {
      __builtin_amdgcn_global_load_lds(
          (const __attribute__((address_space(1))) u32*)(g + it * 1024 + lane * 16),
          (__attribute__((address_space(3))) u32*)(sbuf + wave * 4096 + it * 1024),
          16, 0, 0);
    }
    __syncthreads();
#pragma unroll
    for (int t32 = 0; t32 < 2; ++t32) {
      const int gcode = scb + ib * 64 + t32 * 32 + m;
      float enl = en[gcode];
      f32x16 acc;
#pragma unroll
      for (int r = 0; r < 16; ++r) acc[r] = 0.f;
      const unsigned char* sb = sbuf + t32 * 8192 + h * 512 + m * 16;
#pragma unroll
      for (int ks = 0; ks < 4; ++ks) {
        bf16x8 bh = *(const bf16x8*)(sb + (size_t)(ks * 2 + 0) * 1024);
        bf16x8 bl = *(const bf16x8*)(sb + (size_t)(ks * 2 + 1) * 1024);
        acc = __builtin_amdgcn_mfma_f32_32x32x16_bf16(ahi[ks], bh, acc, 0, 0, 0);
        acc = __builtin_amdgcn_mfma_f32_32x32x16_bf16(alo[ks], bh, acc, 0, 0, 0);
        acc = __builtin_amdgcn_mfma_f32_32x32x16_bf16(ahi[ks], bl, acc, 0, 0, 0);
      }
      float fidx = (float)gcode;
#pragma unroll
      for (int r = 0; r < 16; ++r) {
        // 5-op top-2 update: b2' = max(b2, min(b1,s)); b1' = max(b1,s)
        float s = acc[r] - enl;
        b2[r] = fmaxf(b2[r], fminf(b1[r], s));
        bool bt = s > b1[r];                  // strict >, ascending codes
        i1[r] = bt ? fidx : i1[r];
        b1[r] = fmaxf(b1[r], s);
      }
    }
    __syncthreads();
  }
#pragma unroll
  for (int st = 1; st < 32; st <<= 1) {
#pragma unroll
    for (int r = 0; r < 16; ++r) {
      float ob1 = __shfl_xor(b1[r], st, 64);
      float oi1 = __shfl_xor(i1[r], st, 64);
      float ob2 = __shfl_xor(b2[r], st, 64);
      bool ogt = (ob1 > b1[r]) || (ob1 == b1[r] && oi1 < i1[r]);
      float loser = ogt ? b1[r] : ob1;
      b2[r] = fmaxf(loser, fmaxf(b2[r], ob2));
      b1[r] = ogt ? ob1 : b1[r];
      i1[r] = ogt ? oi1 : i1[r];
    }
  }
  if (m == 0) {
#pragma unroll
    for (int r = 0; r < 16; ++r) {
      int row = (r & 3) + 8 * (r >> 2) + 4 * h;   // C/D row map [m74/m101]
      int token = token0 + row;
      best1[token * 4 + sl] = enc_pair(b1[r], (int)i1[r]);
      best2[token * 4 + sl] = b2[r];
    }
  }
}

// ---- merge slices, pick top1, flag ambiguous tokens ---------------------
__global__ __launch_bounds__(256) void k_resolve(const u64* __restrict__ best1,
                                                 const float* __restrict__ best2,
                                                 int* __restrict__ idxa,
                                                 int* __restrict__ list,
                                                 int* __restrict__ cnt) {
  int n = blockIdx.x * 256 + threadIdx.x;   // 16384
  u64 e0 = best1[n * 4 + 0], e1 = best1[n * 4 + 1];
  u64 e2 = best1[n * 4 + 2], e3 = best1[n * 4 + 3];
  u64 m01 = e0 > e1 ? e0 : e1, m23 = e2 > e3 ? e2 : e3;
  u64 top = m01 > m23 ? m01 : m23;
  float second = fmaxf(fmaxf(best2[n * 4 + 0], best2[n * 4 + 1]),
                       fmaxf(best2[n * 4 + 2], best2[n * 4 + 3]));
  if (e0 != top) second = fmaxf(second, dec_score(e0));
  if (e1 != top) second = fmaxf(second, dec_score(e1));
  if (e2 != top) second = fmaxf(second, dec_score(e2));
  if (e3 != top) second = fmaxf(second, dec_score(e3));
  idxa[n] = dec_idx(top);
  if (dec_score(top) - second < TAU) {
    int p = atomicAdd(cnt, 1);
    list[p] = n;
  }
}

// ---- exact fp32 rescan for ambiguous tokens (R1 bit-exact fmaf chain) ---
// grid-stride over tokens: 1 token per block -> ~count concurrent blocks
__global__ __launch_bounds__(256) void k_fixup(const float* __restrict__ z_e,
                                               const float* __restrict__ emb,
                                               const float* __restrict__ en,
                                               const int* __restrict__ list,
                                               const int* __restrict__ cnt,
                                               int* __restrict__ idxa) {
  __shared__ float sx[64];
  __shared__ u64 red[256];
  int count = *cnt;
  for (int i = blockIdx.x; i < count; i += gridDim.x) {
    int n = list[i];
    __syncthreads();
    if (threadIdx.x < 64) {
      sx[threadIdx.x] = z_e[((size_t)(n >> 10) << 16)
                            + ((size_t)threadIdx.x << 10) + (n & 1023)];
    }
    __syncthreads();
    float x[64];
#pragma unroll
    for (int c = 0; c < 64; ++c) x[c] = sx[c];
    u64 best = 0;
    for (int k0 = threadIdx.x; k0 < 8192; k0 += 512) {
      int k1 = k0 + 256;
      const float4* e0 = (const float4*)(emb + (size_t)k0 * 64);
      const float4* e1 = (const float4*)(emb + (size_t)k1 * 64);
      float a0 = 0.f, a1 = 0.f;   // two independent chains, each c-ascending
#pragma unroll
      for (int q = 0; q < 16; ++q) {
        float4 v0 = e0[q], v1 = e1[q];
        a0 = fmaf(x[4 * q], v0.x, a0);
        a0 = fmaf(x[4 * q + 1], v0.y, a0);
        a0 = fmaf(x[4 * q + 2], v0.z, a0);
        a0 = fmaf(x[4 * q + 3], v0.w, a0);
        a1 = fmaf(x[4 * q], v1.x, a1);
        a1 = fmaf(x[4 * q + 1], v1.y, a1);
        a1 = fmaf(x[4 * q + 2], v1.z, a1);
        a1 = fmaf(x[4 * q + 3], v1.w, a1);
      }
      a0 -= en[k0];
      a1 -= en[k1];
      u64 enc0 = enc_pair(a0, k0);
      u64 enc1 = enc_pair(a1, k1);
      u64 m = enc0 > enc1 ? enc0 : enc1;
      best = best > m ? best : m;
    }
    red[threadIdx.x] = best;
    __syncthreads();
    for (int st = 128; st > 0; st >>= 1) {
      if (threadIdx.x < st) {
        u64 o = red[threadIdx.x + st];
        if (o > red[threadIdx.x]) red[threadIdx.x] = o;
      }
      __syncthreads();
    }
    if (threadIdx.x == 0) idxa[n] = dec_idx(red[0]);
    __syncthreads();
  }
}

// ---- fused gather (z_q, z_q_st, indices) + EMA scatter -------------------
__global__ __launch_bounds__(256) void k_gather_scatter(
    const float* __restrict__ z_e, const float* __restrict__ emb,
    const int* __restrict__ idxa, float* __restrict__ out0,
    float* __restrict__ out1, float* __restrict__ out2,
    float* __restrict__ out4, float* __restrict__ out5) {
  int tid = blockIdx.x * 256 + threadIdx.x;   // 262144 = 16 b x 64 c x 256 hw4
  int hw4 = tid & 255;
  int c   = (tid >> 8) & 63;
  int b   = tid >> 14;
  int n0  = (b << 10) + (hw4 << 2);
  size_t off = ((size_t)b << 16) + ((size_t)c << 10) + ((size_t)hw4 << 2);
  float4 z = *(const float4*)(z_e + off);
  int i0 = idxa[n0], i1 = idxa[n0 + 1], i2 = idxa[n0 + 2], i3 = idxa[n0 + 3];
  float4 q;
  q.x = emb[(size_t)i0 * 64 + c];
  q.y = emb[(size_t)i1 * 64 + c];
  q.z = emb[(size_t)i2 * 64 + c];
  q.w = emb[(size_t)i3 * 64 + c];
  float4 st;
  st.x = z.x + (q.x - z.x);
  st.y = z.y + (q.y - z.y);
  st.z = z.z + (q.z - z.z);
  st.w = z.w + (q.w - z.w);
  *(float4*)(out2 + off) = q;
  *(float4*)(out0 + off) = st;
  // EMA scatter: dw and counts
  atomicAdd(out5 + (size_t)i0 * 64 + c, OMDF * z.x);
  atomicAdd(out5 + (size_t)i1 * 64 + c, OMDF * z.y);
  atomicAdd(out5 + (size_t)i2 * 64 + c, OMDF * z.z);
  atomicAdd(out5 + (size_t)i3 * 64 + c, OMDF * z.w);
  if (c == 0) {
    float4 f = make_float4((float)i0, (float)i1, (float)i2, (float)i3);
    *(float4*)(out1 + n0) = f;
    atomicAdd(out4 + i0, OMDF);
    atomicAdd(out4 + i1, OMDF);
    atomicAdd(out4 + i2, OMDF);
    atomicAdd(out4 + i3, OMDF);
  }
}

// ---- n = sum(new_cluster_size) ------------------------------------------
__global__ __launch_bounds__(256) void k_sum(const float* __restrict__ out4,
                                             float* __restrict__ nsum) {
  int tid = blockIdx.x * 256 + threadIdx.x;
  float v = out4[tid];
  v += __shfl_xor(v, 1, 64);
  v += __shfl_xor(v, 2, 64);
  v += __shfl_xor(v, 4, 64);
  v += __shfl_xor(v, 8, 64);
  v += __shfl_xor(v, 16, 64);
  v += __shfl_xor(v, 32, 64);
  if ((threadIdx.x & 63) == 0) atomicAdd(nsum, v);
}

// ---- new_embedding = new_embedding_avg / cs -----------------------------
__global__ __launch_bounds__(256) void k_final(const float* __restrict__ out4,
                                               const float* __restrict__ out5,
                                               const float* __restrict__ nsum,
                                               float* __restrict__ out3) {
  int tid = blockIdx.x * 256 + threadIdx.x;
  int k = tid >> 4;
  double nn  = (double)*nsum;
  double ncs = (double)out4[k];
  double cs  = (ncs + 1e-5) / (nn + 8192.0 * 1e-5) * nn;
  float inv  = (float)(1.0 / cs);
  float4 v = ((const float4*)out5)[tid];
  v.x *= inv; v.y *= inv; v.z *= inv; v.w *= inv;
  ((float4*)out3)[tid] = v;
}

extern "C" void kernel_launch(void* const* d_in, const int* in_sizes, int n_in,
                              void* d_out, int out_size, void* d_ws, size_t ws_size,
                              hipStream_t stream) {
  const float* z_e    = (const float*)d_in[0];
  const float* emb    = (const float*)d_in[1];
  const float* cs_in  = (const float*)d_in[2];
  const float* avg_in = (const float*)d_in[3];

  float* out  = (float*)d_out;
  float* out0 = out;                    // z_q_st        1048576
  float* out1 = out0 + 1048576;         // indices(f32)  16384
  float* out2 = out1 + 16384;           // z_q           1048576
  float* out3 = out2 + 1048576;         // new_embedding 524288
  float* out4 = out3 + 524288;          // new_cluster   8192
  float* out5 = out4 + 8192;            // new_emb_avg   524288

  char* ws = (char*)d_ws;
  float* en            = (float*)(ws + EN_OFF);
  unsigned char* efrag = (unsigned char*)(ws + EFRAG_OFF);
  u64* best1           = (u64*)(ws + BEST1_OFF);
  float* best2         = (float*)(ws + BEST2_OFF);
  int* idxa            = (int*)(ws + IDX_OFF);
  int* list            = (int*)(ws + LIST_OFF);
  int* cnt             = (int*)(ws + CNT_OFF);
  float* nsum          = (float*)(ws + CNT_OFF + 4);

  hipMemsetAsync(ws + CNT_OFF, 0, 8, stream);    // cnt + nsum

  k_en_eprep     <<<512,  256, 0, stream>>>(emb, en, efrag);
  k_init         <<<520,  256, 0, stream>>>(cs_in, avg_in, out4, out5);
  k_argmin_mfma  <<<512,  256, 0, stream>>>(z_e, efrag, en, best1, best2);
  k_resolve      <<<64,   256, 0, stream>>>(best1, best2, idxa, list, cnt);
  k_fixup        <<<2048, 256, 0, stream>>>(z_e, emb, en, list, cnt, idxa);
  k_gather_scatter<<<1024, 256, 0, stream>>>(z_e, emb, idxa, out0, out1, out2,
                                             out4, out5);
  k_sum          <<<32,   256, 0, stream>>>(out4, nsum);
  k_final        <<<512,  256, 0, stream>>>(out4, out5, nsum, out3);
}

// Round 4
// 229.439 us; speedup vs baseline: 1.3755x; 1.3755x over previous
//
#include <hip/hip_runtime.h>

// Problem: B=16,C=64,H=32,W=32 -> N=16384 tokens; K=8192 codes.
#define DECAYF 0.99f
#define OMDF   0.01f
#define TAU    1.0e-2f    // > quantize step (<=1e-3) + split-bf16 err (<=5e-4), x5 margin

typedef unsigned int u32;
typedef unsigned long long u64;
typedef __attribute__((ext_vector_type(8))) short bf16x8;   // 8 bf16 (4 VGPRs)
typedef __attribute__((ext_vector_type(16))) float f32x16;  // MFMA 32x32 acc

// ws layout (bytes)
#define EN_OFF     0              // en[8192] f32: 0.5*||e||^2
#define EFRAG_OFF  32768          // 4 MB frag-ordered bf16 hi/lo of emb
#define BEST1_OFF  4227072        // u64 [16384][4] per-(token,slice) best (enc)
#define BEST2_OFF  4751360        // f32 [16384][4] per-(token,slice) 2nd-best score
#define IDX_OFF    5013504        // i32 [16384] final indices
#define LIST_OFF   5079040        // i32 [16384] ambiguous-token list
#define CNT_OFF    5144576        // i32 count ; +4: f32 nsum (partial: 0.99*sum(cs_in))

__device__ __forceinline__ u64 enc_pair(float s, int idx) {
  u32 u = __float_as_uint(s);
  u = (u & 0x80000000u) ? ~u : (u | 0x80000000u);   // order-preserving
  return ((u64)u << 32) | (u32)(~idx);              // ~idx: ties -> min idx
}
__device__ __forceinline__ float dec_score(u64 e) {
  u32 u = (u32)(e >> 32);
  u = (u & 0x80000000u) ? (u & 0x7fffffffu) : ~u;
  return __uint_as_float(u);
}
__device__ __forceinline__ int dec_idx(u64 e) { return (int)(~(u32)e); }
__device__ __forceinline__ unsigned short f2bf(float f) {  // f32 -> bf16 RNE
  u32 u = __float_as_uint(f);
  u += 0x7fffu + ((u >> 16) & 1u);
  return (unsigned short)(u >> 16);
}

// ---- fused: en = 0.5*||e||^2 (R1 bit-exact) + emb -> bf16 hi/lo frags ----
// frag layout: [tile32][kstep*2+split][h][n32][j]  (1024 B per kstep-split)
__global__ __launch_bounds__(256) void k_en_eprep(const float* __restrict__ emb,
                                                  float* __restrict__ en,
                                                  unsigned char* __restrict__ efrag,
                                                  int* __restrict__ cnt,
                                                  float* __restrict__ nsum) {
  int tid = blockIdx.x * 256 + threadIdx.x;   // 131072 float4s
  if (tid == 0) { *cnt = 0; *nsum = 0.f; }    // replaces hipMemsetAsync
  int k = tid >> 4, q = tid & 15;
  float4 v = ((const float4*)emb)[tid];
  int kstep = q >> 2, h = (q >> 1) & 1, j0 = (q & 1) * 4;
  int tile = k >> 5, n32 = k & 31;
  ushort4 hi, lo;
  hi.x = f2bf(v.x); lo.x = f2bf(v.x - __uint_as_float((u32)hi.x << 16));
  hi.y = f2bf(v.y); lo.y = f2bf(v.y - __uint_as_float((u32)hi.y << 16));
  hi.z = f2bf(v.z); lo.z = f2bf(v.z - __uint_as_float((u32)hi.z << 16));
  hi.w = f2bf(v.w); lo.w = f2bf(v.w - __uint_as_float((u32)hi.w << 16));
  size_t off = (size_t)tile * 8192 + (size_t)(kstep * 2) * 1024
             + (size_t)h * 512 + (size_t)n32 * 16 + (size_t)j0 * 2;
  *(ushort4*)(efrag + off)        = hi;   // split 0 (hi)
  *(ushort4*)(efrag + off + 1024) = lo;   // split 1 (lo)
  float s = v.x * v.x + v.y * v.y + v.z * v.z + v.w * v.w;
  s += __shfl_xor(s, 1, 16);
  s += __shfl_xor(s, 2, 16);
  s += __shfl_xor(s, 4, 16);
  s += __shfl_xor(s, 8, 16);
  if (q == 0) en[k] = 0.5f * s;
}

// ---- init EMA outputs + partial n = 0.99*sum(cs_in) ----------------------
__global__ __launch_bounds__(256) void k_init(const float* __restrict__ cs_in,
                                              const float* __restrict__ avg_in,
                                              float* __restrict__ out4,
                                              float* __restrict__ out5,
                                              float* __restrict__ nsum) {
  int tid = blockIdx.x * 256 + threadIdx.x;
  if (tid < 131072) {
    float4 v = ((const float4*)avg_in)[tid];
    v.x *= DECAYF; v.y *= DECAYF; v.z *= DECAYF; v.w *= DECAYF;
    ((float4*)out5)[tid] = v;
  } else {
    int t = tid - 131072;                      // 2048 float4s of cluster_size
    float4 v = ((const float4*)cs_in)[t];
    v.x *= DECAYF; v.y *= DECAYF; v.z *= DECAYF; v.w *= DECAYF;
    ((float4*)out4)[t] = v;
    float s = v.x + v.y + v.z + v.w;           // already x0.99
    s += __shfl_xor(s, 1, 64);
    s += __shfl_xor(s, 2, 64);
    s += __shfl_xor(s, 4, 64);
    s += __shfl_xor(s, 8, 64);
    s += __shfl_xor(s, 16, 64);
    s += __shfl_xor(s, 32, 64);
    if ((threadIdx.x & 63) == 0) atomicAdd(nsum, s);
  }
}

// ---- MFMA argmin: 32x32x16 bf16 split hi/lo; sub-idx packed in mantissa --
__global__ __launch_bounds__(256) void k_argmin_mfma(
    const float* __restrict__ z_e, const unsigned char* __restrict__ efrag,
    const float* __restrict__ en, u64* __restrict__ best1,
    float* __restrict__ best2) {
  alignas(16) __shared__ unsigned char sbuf[16384];   // 64 codes, frag order
  const int tb = blockIdx.x >> 2;            // token group (128 tokens)
  const int sl = blockIdx.x & 3;             // K-slice
  const int wave = threadIdx.x >> 6, lane = threadIdx.x & 63;
  const int h = lane >> 5, m = lane & 31;
  const int token0 = tb * 128 + wave * 32;

  bf16x8 ahi[4], alo[4];
  {
    const int token = token0 + m;
    const float* zp = z_e + ((size_t)(token >> 10) << 16) + (token & 1023);
#pragma unroll
    for (int ks = 0; ks < 4; ++ks) {
#pragma unroll
      for (int j = 0; j < 8; ++j) {
        int c = ks * 16 + h * 8 + j;
        float x = zp[(size_t)c << 10];
        unsigned short xh = f2bf(x);
        ahi[ks][j] = (short)xh;
        alo[ks][j] = (short)f2bf(x - __uint_as_float((u32)xh << 16));
      }
    }
  }
  float b1[16], b2[16];
#pragma unroll
  for (int r = 0; r < 16; ++r) { b1[r] = -3.0e38f; b2[r] = -3.0e38f; }

  const int scb = sl * 2048;
  const unsigned char* gbase0 = efrag + (size_t)scb * 256;   // 256 B/code
  for (int ib = 0; ib < 32; ++ib) {
    const unsigned char* g = gbase0 + (size_t)ib * 16384 + (size_t)wave * 4096;
#pragma unroll
    for (int it = 0; it < 4; ++it) {
      __builtin_amdgcn_global_load_lds(
          (const __attribute__((address_space(1))) u32*)(g + it * 1024 + lane * 16),
          (__attribute__((address_space(3))) u32*)(sbuf + wave * 4096 + it * 1024),
          16, 0, 0);
    }
    __syncthreads();
#pragma unroll
    for (int t32 = 0; t32 < 2; ++t32) {
      const int t = ib * 2 + t32;               // 0..63 sub-tile id in slice
      const float enl = en[scb + t * 32 + m];
      f32x16 acc;
#pragma unroll
      for (int r = 0; r < 16; ++r) acc[r] = 0.f;
      const unsigned char* sb = sbuf + t32 * 8192 + h * 512 + m * 16;
#pragma unroll
      for (int ks = 0; ks < 4; ++ks) {
        bf16x8 bh = *(const bf16x8*)(sb + (size_t)(ks * 2 + 0) * 1024);
        bf16x8 bl = *(const bf16x8*)(sb + (size_t)(ks * 2 + 1) * 1024);
        acc = __builtin_amdgcn_mfma_f32_32x32x16_bf16(ahi[ks], bh, acc, 0, 0, 0);
        acc = __builtin_amdgcn_mfma_f32_32x32x16_bf16(alo[ks], bh, acc, 0, 0, 0);
        acc = __builtin_amdgcn_mfma_f32_32x32x16_bf16(ahi[ks], bl, acc, 0, 0, 0);
      }
      const u32 emb6 = (u32)(63 - t);           // sub-idx in low 6 mantissa bits
#pragma unroll
      for (int r = 0; r < 16; ++r) {
        float s = acc[r] - enl;                                   // v_sub
        float f = __uint_as_float((__float_as_uint(s) & 0xFFFFFFC0u) | emb6); // v_and_or
        b2[r] = __builtin_amdgcn_fmed3f(f, b1[r], b2[r]);         // v_med3
        b1[r] = fmaxf(b1[r], f);                                  // v_max
      }
    }
    __syncthreads();
  }
  // cross-lane top-2 merge over the 32 code-class lanes (same h half)
  int mi[16];
#pragma unroll
  for (int r = 0; r < 16; ++r) mi[r] = m;
#pragma unroll
  for (int st = 1; st < 32; st <<= 1) {
#pragma unroll
    for (int r = 0; r < 16; ++r) {
      float ob1 = __shfl_xor(b1[r], st, 64);
      float ob2 = __shfl_xor(b2[r], st, 64);
      int omi = __shfl_xor(mi[r], st, 64);
      bool ogt = ob1 > b1[r];            // strict: equal -> quantized tie -> fixup
      b2[r] = fmaxf(fminf(b1[r], ob1), fmaxf(b2[r], ob2));
      mi[r] = ogt ? omi : mi[r];
      b1[r] = fmaxf(b1[r], ob1);
    }
  }
  if (m == 0) {     // lanes 0 and 32: 16 token-rows each
#pragma unroll
    for (int r = 0; r < 16; ++r) {
      int row = (r & 3) + 8 * (r >> 2) + 4 * h;   // C/D row map [m74/m101]
      int token = token0 + row;
      int t = 63 - (int)(__float_as_uint(b1[r]) & 63u);
      int gcode = scb + t * 32 + mi[r];
      best1[token * 4 + sl] = enc_pair(b1[r], gcode);
      best2[token * 4 + sl] = b2[r];
    }
  }
}

// ---- merge slices, pick top1, flag ambiguous tokens ---------------------
__global__ __launch_bounds__(256) void k_resolve(const u64* __restrict__ best1,
                                                 const float* __restrict__ best2,
                                                 int* __restrict__ idxa,
                                                 int* __restrict__ list,
                                                 int* __restrict__ cnt) {
  int n = blockIdx.x * 256 + threadIdx.x;   // 16384
  u64 e0 = best1[n * 4 + 0], e1 = best1[n * 4 + 1];
  u64 e2 = best1[n * 4 + 2], e3 = best1[n * 4 + 3];
  u64 m01 = e0 > e1 ? e0 : e1, m23 = e2 > e3 ? e2 : e3;
  u64 top = m01 > m23 ? m01 : m23;
  float second = fmaxf(fmaxf(best2[n * 4 + 0], best2[n * 4 + 1]),
                       fmaxf(best2[n * 4 + 2], best2[n * 4 + 3]));
  if (e0 != top) second = fmaxf(second, dec_score(e0));
  if (e1 != top) second = fmaxf(second, dec_score(e1));
  if (e2 != top) second = fmaxf(second, dec_score(e2));
  if (e3 != top) second = fmaxf(second, dec_score(e3));
  idxa[n] = dec_idx(top);
  if (dec_score(top) - second < TAU) {
    int p = atomicAdd(cnt, 1);
    list[p] = n;
  }
}

// ---- exact fp32 rescan for ambiguous tokens (R1 bit-exact fmaf chain) ---
__global__ __launch_bounds__(256) void k_fixup(const float* __restrict__ z_e,
                                               const float* __restrict__ emb,
                                               const float* __restrict__ en,
                                               const int* __restrict__ list,
                                               const int* __restrict__ cnt,
                                               int* __restrict__ idxa) {
  __shared__ float sx[64];
  __shared__ u64 red[256];
  int count = *cnt;
  for (int i = blockIdx.x; i < count; i += gridDim.x) {
    int n = list[i];
    __syncthreads();
    if (threadIdx.x < 64) {
      sx[threadIdx.x] = z_e[((size_t)(n >> 10) << 16)
                            + ((size_t)threadIdx.x << 10) + (n & 1023)];
    }
    __syncthreads();
    float x[64];
#pragma unroll
    for (int c = 0; c < 64; ++c) x[c] = sx[c];
    u64 best = 0;
    for (int k0 = threadIdx.x; k0 < 8192; k0 += 512) {
      int k1 = k0 + 256;
      const float4* e0 = (const float4*)(emb + (size_t)k0 * 64);
      const float4* e1 = (const float4*)(emb + (size_t)k1 * 64);
      float a0 = 0.f, a1 = 0.f;   // two independent chains, each c-ascending
#pragma unroll
      for (int q = 0; q < 16; ++q) {
        float4 v0 = e0[q], v1 = e1[q];
        a0 = fmaf(x[4 * q], v0.x, a0);
        a0 = fmaf(x[4 * q + 1], v0.y, a0);
        a0 = fmaf(x[4 * q + 2], v0.z, a0);
        a0 = fmaf(x[4 * q + 3], v0.w, a0);
        a1 = fmaf(x[4 * q], v1.x, a1);
        a1 = fmaf(x[4 * q + 1], v1.y, a1);
        a1 = fmaf(x[4 * q + 2], v1.z, a1);
        a1 = fmaf(x[4 * q + 3], v1.w, a1);
      }
      a0 -= en[k0];
      a1 -= en[k1];
      u64 enc0 = enc_pair(a0, k0);
      u64 enc1 = enc_pair(a1, k1);
      u64 mx = enc0 > enc1 ? enc0 : enc1;
      best = best > mx ? best : mx;
    }
    red[threadIdx.x] = best;
    __syncthreads();
    for (int st = 128; st > 0; st >>= 1) {
      if (threadIdx.x < st) {
        u64 o = red[threadIdx.x + st];
        if (o > red[threadIdx.x]) red[threadIdx.x] = o;
      }
      __syncthreads();
    }
    if (threadIdx.x == 0) idxa[n] = dec_idx(red[0]);
    __syncthreads();
  }
}

// ---- scatter EMA stats (R1 layout: lane = channel -> coalesced atomics) --
__global__ __launch_bounds__(256) void k_scatter(const float* __restrict__ z_e,
                                                 const int* __restrict__ idxa,
                                                 float* __restrict__ out4,
                                                 float* __restrict__ out5) {
  int tid = blockIdx.x * 256 + threadIdx.x;   // 1M = 16384 tokens x 64 ch
  int n = tid >> 6, c = tid & 63;
  int idx = idxa[n];
  int b = n >> 10, hw = n & 1023;
  float x = z_e[((size_t)b << 16) + ((size_t)c << 10) + hw];
  atomicAdd(out5 + (size_t)idx * 64 + c, OMDF * x);
  if (c == 0) atomicAdd(out4 + idx, OMDF);
}

// ---- gather z_q / z_q_st / indices --------------------------------------
__global__ __launch_bounds__(256) void k_gather(const float* __restrict__ z_e,
                                                const float* __restrict__ emb,
                                                const int* __restrict__ idxa,
                                                float* __restrict__ out0,
                                                float* __restrict__ out1,
                                                float* __restrict__ out2) {
  int tid = blockIdx.x * 256 + threadIdx.x;   // 262144 = 16 b x 64 c x 256 hw4
  int hw4 = tid & 255;
  int c   = (tid >> 8) & 63;
  int b   = tid >> 14;
  int n0  = (b << 10) + (hw4 << 2);
  size_t off = ((size_t)b << 16) + ((size_t)c << 10) + ((size_t)hw4 << 2);
  float4 z = *(const float4*)(z_e + off);
  int i0 = idxa[n0], i1 = idxa[n0 + 1], i2 = idxa[n0 + 2], i3 = idxa[n0 + 3];
  float4 q;
  q.x = emb[(size_t)i0 * 64 + c];
  q.y = emb[(size_t)i1 * 64 + c];
  q.z = emb[(size_t)i2 * 64 + c];
  q.w = emb[(size_t)i3 * 64 + c];
  float4 st;
  st.x = z.x + (q.x - z.x);
  st.y = z.y + (q.y - z.y);
  st.z = z.z + (q.z - z.z);
  st.w = z.w + (q.w - z.w);
  *(float4*)(out2 + off) = q;
  *(float4*)(out0 + off) = st;
  if (c == 0) {
    float4 f = make_float4((float)i0, (float)i1, (float)i2, (float)i3);
    *(float4*)(out1 + n0) = f;
  }
}

// ---- new_embedding = new_embedding_avg / cs -----------------------------
// n = 0.99*sum(cs_in) [in nsum] + 0.01*16384 (sum of counts == N exactly)
__global__ __launch_bounds__(256) void k_final(const float* __restrict__ out4,
                                               const float* __restrict__ out5,
                                               const float* __restrict__ nsum,
                                               float* __restrict__ out3) {
  int tid = blockIdx.x * 256 + threadIdx.x;
  int k = tid >> 4;
  double nn  = (double)*nsum + 163.84;
  double ncs = (double)out4[k];
  double cs  = (ncs + 1e-5) / (nn + 8192.0 * 1e-5) * nn;
  float inv  = (float)(1.0 / cs);
  float4 v = ((const float4*)out5)[tid];
  v.x *= inv; v.y *= inv; v.z *= inv; v.w *= inv;
  ((float4*)out3)[tid] = v;
}

extern "C" void kernel_launch(void* const* d_in, const int* in_sizes, int n_in,
                              void* d_out, int out_size, void* d_ws, size_t ws_size,
                              hipStream_t stream) {
  const float* z_e    = (const float*)d_in[0];
  const float* emb    = (const float*)d_in[1];
  const float* cs_in  = (const float*)d_in[2];
  const float* avg_in = (const float*)d_in[3];

  float* out  = (float*)d_out;
  float* out0 = out;                    // z_q_st        1048576
  float* out1 = out0 + 1048576;         // indices(f32)  16384
  float* out2 = out1 + 16384;           // z_q           1048576
  float* out3 = out2 + 1048576;         // new_embedding 524288
  float* out4 = out3 + 524288;          // new_cluster   8192
  float* out5 = out4 + 8192;            // new_emb_avg   524288

  char* ws = (char*)d_ws;
  float* en            = (float*)(ws + EN_OFF);
  unsigned char* efrag = (unsigned char*)(ws + EFRAG_OFF);
  u64* best1           = (u64*)(ws + BEST1_OFF);
  float* best2         = (float*)(ws + BEST2_OFF);
  int* idxa            = (int*)(ws + IDX_OFF);
  int* list            = (int*)(ws + LIST_OFF);
  int* cnt             = (int*)(ws + CNT_OFF);
  float* nsum          = (float*)(ws + CNT_OFF + 4);

  k_en_eprep   <<<512,  256, 0, stream>>>(emb, en, efrag, cnt, nsum);
  k_init       <<<520,  256, 0, stream>>>(cs_in, avg_in, out4, out5, nsum);
  k_argmin_mfma<<<512,  256, 0, stream>>>(z_e, efrag, en, best1, best2);
  k_resolve    <<<64,   256, 0, stream>>>(best1, best2, idxa, list, cnt);
  k_fixup      <<<1024, 256, 0, stream>>>(z_e, emb, en, list, cnt, idxa);
  k_scatter    <<<4096, 256, 0, stream>>>(z_e, idxa, out4, out5);
  k_gather     <<<1024, 256, 0, stream>>>(z_e, emb, idxa, out0, out1, out2);
  k_final      <<<512,  256, 0, stream>>>(out4, out5, nsum, out3);
}

// Round 5
// 194.331 us; speedup vs baseline: 1.6240x; 1.1807x over previous
//
#include <hip/hip_runtime.h>

// Problem: B=16,C=64,H=32,W=32 -> N=16384 tokens; K=8192 codes.
#define DECAYF 0.99f
#define OMDF   0.01f
#define TAU    1.0e-2f    // > quantize step (<=1e-3) + split-bf16 err (<=5e-4), x5 margin

typedef unsigned int u32;
typedef unsigned long long u64;
typedef __attribute__((ext_vector_type(8))) short bf16x8;   // 8 bf16 (4 VGPRs)
typedef __attribute__((ext_vector_type(16))) float f32x16;  // MFMA 32x32 acc

// ws layout (bytes)
#define EN_OFF     0              // en[8192] f32: 0.5*||e||^2
#define EFRAG_OFF  32768          // 4 MB frag-ordered bf16 hi/lo of emb
#define BEST1_OFF  4227072        // u64 [16384][4] per-(token,slice) best (enc)
#define BEST2_OFF  4751360        // f32 [16384][4] per-(token,slice) 2nd-best score
#define IDX_OFF    5013504        // i32 [16384] final indices
#define LIST_OFF   5079040        // i32 [16384] ambiguous-token list
#define CNT_OFF    5144576        // i32 count ; +4: f32 nsum (partial: 0.99*sum(cs_in))
#define CELL_OFF   5144584        // u64 [16384] exact-score cells for listed tokens

__device__ __forceinline__ u64 enc_pair(float s, int idx) {
  u32 u = __float_as_uint(s);
  u = (u & 0x80000000u) ? ~u : (u | 0x80000000u);   // order-preserving
  return ((u64)u << 32) | (u32)(~idx);              // ~idx: ties -> min idx
}
__device__ __forceinline__ float dec_score(u64 e) {
  u32 u = (u32)(e >> 32);
  u = (u & 0x80000000u) ? (u & 0x7fffffffu) : ~u;
  return __uint_as_float(u);
}
__device__ __forceinline__ int dec_idx(u64 e) { return (int)(~(u32)e); }
__device__ __forceinline__ unsigned short f2bf(float f) {  // f32 -> bf16 RNE
  u32 u = __float_as_uint(f);
  u += 0x7fffu + ((u >> 16) & 1u);
  return (unsigned short)(u >> 16);
}

// ---- fused: en = 0.5*||e||^2 (R1 bit-exact) + emb -> bf16 hi/lo frags ----
__global__ __launch_bounds__(256) void k_en_eprep(const float* __restrict__ emb,
                                                  float* __restrict__ en,
                                                  unsigned char* __restrict__ efrag,
                                                  int* __restrict__ cnt,
                                                  float* __restrict__ nsum) {
  int tid = blockIdx.x * 256 + threadIdx.x;   // 131072 float4s
  if (tid == 0) { *cnt = 0; *nsum = 0.f; }
  int k = tid >> 4, q = tid & 15;
  float4 v = ((const float4*)emb)[tid];
  int kstep = q >> 2, h = (q >> 1) & 1, j0 = (q & 1) * 4;
  int tile = k >> 5, n32 = k & 31;
  ushort4 hi, lo;
  hi.x = f2bf(v.x); lo.x = f2bf(v.x - __uint_as_float((u32)hi.x << 16));
  hi.y = f2bf(v.y); lo.y = f2bf(v.y - __uint_as_float((u32)hi.y << 16));
  hi.z = f2bf(v.z); lo.z = f2bf(v.z - __uint_as_float((u32)hi.z << 16));
  hi.w = f2bf(v.w); lo.w = f2bf(v.w - __uint_as_float((u32)hi.w << 16));
  size_t off = (size_t)tile * 8192 + (size_t)(kstep * 2) * 1024
             + (size_t)h * 512 + (size_t)n32 * 16 + (size_t)j0 * 2;
  *(ushort4*)(efrag + off)        = hi;   // split 0 (hi)
  *(ushort4*)(efrag + off + 1024) = lo;   // split 1 (lo)
  float s = v.x * v.x + v.y * v.y + v.z * v.z + v.w * v.w;
  s += __shfl_xor(s, 1, 16);
  s += __shfl_xor(s, 2, 16);
  s += __shfl_xor(s, 4, 16);
  s += __shfl_xor(s, 8, 16);
  if (q == 0) en[k] = 0.5f * s;
}

// ---- init EMA outputs + partial n = 0.99*sum(cs_in) ----------------------
__global__ __launch_bounds__(256) void k_init(const float* __restrict__ cs_in,
                                              const float* __restrict__ avg_in,
                                              float* __restrict__ out4,
                                              float* __restrict__ out5,
                                              float* __restrict__ nsum) {
  int tid = blockIdx.x * 256 + threadIdx.x;
  if (tid < 131072) {
    float4 v = ((const float4*)avg_in)[tid];
    v.x *= DECAYF; v.y *= DECAYF; v.z *= DECAYF; v.w *= DECAYF;
    ((float4*)out5)[tid] = v;
  } else {
    int t = tid - 131072;                      // 2048 float4s of cluster_size
    float4 v = ((const float4*)cs_in)[t];
    v.x *= DECAYF; v.y *= DECAYF; v.z *= DECAYF; v.w *= DECAYF;
    ((float4*)out4)[t] = v;
    float s = v.x + v.y + v.z + v.w;           // already x0.99
    s += __shfl_xor(s, 1, 64);
    s += __shfl_xor(s, 2, 64);
    s += __shfl_xor(s, 4, 64);
    s += __shfl_xor(s, 8, 64);
    s += __shfl_xor(s, 16, 64);
    s += __shfl_xor(s, 32, 64);
    if ((threadIdx.x & 63) == 0) atomicAdd(nsum, s);
  }
}

// ---- MFMA argmin: 32x32x16 bf16 split hi/lo; sub-idx packed in mantissa --
__global__ __launch_bounds__(256) void k_argmin_mfma(
    const float* __restrict__ z_e, const unsigned char* __restrict__ efrag,
    const float* __restrict__ en, u64* __restrict__ best1,
    float* __restrict__ best2) {
  alignas(16) __shared__ unsigned char sbuf[16384];   // 64 codes, frag order
  const int tb = blockIdx.x >> 2;            // token group (128 tokens)
  const int sl = blockIdx.x & 3;             // K-slice
  const int wave = threadIdx.x >> 6, lane = threadIdx.x & 63;
  const int h = lane >> 5, m = lane & 31;
  const int token0 = tb * 128 + wave * 32;

  bf16x8 ahi[4], alo[4];
  {
    const int token = token0 + m;
    const float* zp = z_e + ((size_t)(token >> 10) << 16) + (token & 1023);
#pragma unroll
    for (int ks = 0; ks < 4; ++ks) {
#pragma unroll
      for (int j = 0; j < 8; ++j) {
        int c = ks * 16 + h * 8 + j;
        float x = zp[(size_t)c << 10];
        unsigned short xh = f2bf(x);
        ahi[ks][j] = (short)xh;
        alo[ks][j] = (short)f2bf(x - __uint_as_float((u32)xh << 16));
      }
    }
  }
  float b1[16], b2[16];
#pragma unroll
  for (int r = 0; r < 16; ++r) { b1[r] = -3.0e38f; b2[r] = -3.0e38f; }

  const int scb = sl * 2048;
  const unsigned char* gbase0 = efrag + (size_t)scb * 256;   // 256 B/code
  for (int ib = 0; ib < 32; ++ib) {
    const unsigned char* g = gbase0 + (size_t)ib * 16384 + (size_t)wave * 4096;
#pragma unroll
    for (int it = 0; it < 4; ++it) {
      __builtin_amdgcn_global_load_lds(
          (const __attribute__((address_space(1))) u32*)(g + it * 1024 + lane * 16),
          (__attribute__((address_space(3))) u32*)(sbuf + wave * 4096 + it * 1024),
          16, 0, 0);
    }
    __syncthreads();
#pragma unroll
    for (int t32 = 0; t32 < 2; ++t32) {
      const int t = ib * 2 + t32;               // 0..63 sub-tile id in slice
      const float enl = en[scb + t * 32 + m];
      f32x16 acc;
#pragma unroll
      for (int r = 0; r < 16; ++r) acc[r] = 0.f;
      const unsigned char* sb = sbuf + t32 * 8192 + h * 512 + m * 16;
#pragma unroll
      for (int ks = 0; ks < 4; ++ks) {
        bf16x8 bh = *(const bf16x8*)(sb + (size_t)(ks * 2 + 0) * 1024);
        bf16x8 bl = *(const bf16x8*)(sb + (size_t)(ks * 2 + 1) * 1024);
        acc = __builtin_amdgcn_mfma_f32_32x32x16_bf16(ahi[ks], bh, acc, 0, 0, 0);
        acc = __builtin_amdgcn_mfma_f32_32x32x16_bf16(alo[ks], bh, acc, 0, 0, 0);
        acc = __builtin_amdgcn_mfma_f32_32x32x16_bf16(ahi[ks], bl, acc, 0, 0, 0);
      }
      const u32 emb6 = (u32)(63 - t);           // sub-idx in low 6 mantissa bits
#pragma unroll
      for (int r = 0; r < 16; ++r) {
        float s = acc[r] - enl;                                   // v_sub
        float f = __uint_as_float((__float_as_uint(s) & 0xFFFFFFC0u) | emb6); // v_and_or
        b2[r] = __builtin_amdgcn_fmed3f(f, b1[r], b2[r]);         // v_med3
        b1[r] = fmaxf(b1[r], f);                                  // v_max
      }
    }
    __syncthreads();
  }
  int mi[16];
#pragma unroll
  for (int r = 0; r < 16; ++r) mi[r] = m;
#pragma unroll
  for (int st = 1; st < 32; st <<= 1) {
#pragma unroll
    for (int r = 0; r < 16; ++r) {
      float ob1 = __shfl_xor(b1[r], st, 64);
      float ob2 = __shfl_xor(b2[r], st, 64);
      int omi = __shfl_xor(mi[r], st, 64);
      bool ogt = ob1 > b1[r];            // strict: equal -> quantized tie -> fixup
      b2[r] = fmaxf(fminf(b1[r], ob1), fmaxf(b2[r], ob2));
      mi[r] = ogt ? omi : mi[r];
      b1[r] = fmaxf(b1[r], ob1);
    }
  }
  if (m == 0) {     // lanes 0 and 32: 16 token-rows each
#pragma unroll
    for (int r = 0; r < 16; ++r) {
      int row = (r & 3) + 8 * (r >> 2) + 4 * h;   // C/D row map [m74/m101]
      int token = token0 + row;
      int t = 63 - (int)(__float_as_uint(b1[r]) & 63u);
      int gcode = scb + t * 32 + mi[r];
      best1[token * 4 + sl] = enc_pair(b1[r], gcode);
      best2[token * 4 + sl] = b2[r];
    }
  }
}

// ---- merge slices, pick top1, flag ambiguous tokens ---------------------
__global__ __launch_bounds__(256) void k_resolve(const u64* __restrict__ best1,
                                                 const float* __restrict__ best2,
                                                 int* __restrict__ idxa,
                                                 int* __restrict__ list,
                                                 int* __restrict__ cnt,
                                                 u64* __restrict__ cell) {
  int n = blockIdx.x * 256 + threadIdx.x;   // 16384
  u64 e0 = best1[n * 4 + 0], e1 = best1[n * 4 + 1];
  u64 e2 = best1[n * 4 + 2], e3 = best1[n * 4 + 3];
  u64 m01 = e0 > e1 ? e0 : e1, m23 = e2 > e3 ? e2 : e3;
  u64 top = m01 > m23 ? m01 : m23;
  float second = fmaxf(fmaxf(best2[n * 4 + 0], best2[n * 4 + 1]),
                       fmaxf(best2[n * 4 + 2], best2[n * 4 + 3]));
  if (e0 != top) second = fmaxf(second, dec_score(e0));
  if (e1 != top) second = fmaxf(second, dec_score(e1));
  if (e2 != top) second = fmaxf(second, dec_score(e2));
  if (e3 != top) second = fmaxf(second, dec_score(e3));
  idxa[n] = dec_idx(top);
  if (dec_score(top) - second < TAU) {
    int p = atomicAdd(cnt, 1);
    list[p] = n;
    cell[p] = 0;          // init exact-score cell (separate buffer, no race)
  }
}

// ---- exact fp32 rescan, 8 blocks per ambiguous token (R1-exact chains) --
__global__ __launch_bounds__(256) void k_fixup(const float* __restrict__ z_e,
                                               const float* __restrict__ emb,
                                               const float* __restrict__ en,
                                               const int* __restrict__ list,
                                               const int* __restrict__ cnt,
                                               u64* __restrict__ cell) {
  __shared__ float sx[64];
  __shared__ u64 red[256];
  int count = *cnt;
  for (int j = blockIdx.x; j < count * 8; j += gridDim.x) {
    int i = j >> 3, slice = j & 7;      // token slot, 1024-code slice
    int n = list[i];
    __syncthreads();
    if (threadIdx.x < 64) {
      sx[threadIdx.x] = z_e[((size_t)(n >> 10) << 16)
                            + ((size_t)threadIdx.x << 10) + (n & 1023)];
    }
    __syncthreads();
    float x[64];
#pragma unroll
    for (int c = 0; c < 64; ++c) x[c] = sx[c];
    // 4 codes per thread: kb, kb+256, kb+512, kb+768 (4 independent chains)
    int kb = slice * 1024 + threadIdx.x;
    const float4* e = (const float4*)(emb + (size_t)kb * 64);
    float a0 = 0.f, a1 = 0.f, a2 = 0.f, a3 = 0.f;
#pragma unroll
    for (int q = 0; q < 16; ++q) {
      float4 v0 = e[q], v1 = e[q + 4096], v2 = e[q + 8192], v3 = e[q + 12288];
      a0 = fmaf(x[4 * q], v0.x, a0);
      a0 = fmaf(x[4 * q + 1], v0.y, a0);
      a0 = fmaf(x[4 * q + 2], v0.z, a0);
      a0 = fmaf(x[4 * q + 3], v0.w, a0);
      a1 = fmaf(x[4 * q], v1.x, a1);
      a1 = fmaf(x[4 * q + 1], v1.y, a1);
      a1 = fmaf(x[4 * q + 2], v1.z, a1);
      a1 = fmaf(x[4 * q + 3], v1.w, a1);
      a2 = fmaf(x[4 * q], v2.x, a2);
      a2 = fmaf(x[4 * q + 1], v2.y, a2);
      a2 = fmaf(x[4 * q + 2], v2.z, a2);
      a2 = fmaf(x[4 * q + 3], v2.w, a2);
      a3 = fmaf(x[4 * q], v3.x, a3);
      a3 = fmaf(x[4 * q + 1], v3.y, a3);
      a3 = fmaf(x[4 * q + 2], v3.z, a3);
      a3 = fmaf(x[4 * q + 3], v3.w, a3);
    }
    a0 -= en[kb];
    a1 -= en[kb + 256];
    a2 -= en[kb + 512];
    a3 -= en[kb + 768];
    u64 m0 = enc_pair(a0, kb);
    u64 m1 = enc_pair(a1, kb + 256);
    u64 m2 = enc_pair(a2, kb + 512);
    u64 m3 = enc_pair(a3, kb + 768);
    u64 ma = m0 > m1 ? m0 : m1, mb = m2 > m3 ? m2 : m3;
    red[threadIdx.x] = ma > mb ? ma : mb;
    __syncthreads();
    for (int st = 128; st > 0; st >>= 1) {
      if (threadIdx.x < st) {
        u64 o = red[threadIdx.x + st];
        if (o > red[threadIdx.x]) red[threadIdx.x] = o;
      }
      __syncthreads();
    }
    if (threadIdx.x == 0) atomicMax(&cell[i], red[0]);
  }
}

// ---- write back fixed indices -------------------------------------------
__global__ __launch_bounds__(256) void k_post(const int* __restrict__ list,
                                              const int* __restrict__ cnt,
                                              const u64* __restrict__ cell,
                                              int* __restrict__ idxa) {
  int i = blockIdx.x * 256 + threadIdx.x;
  if (i < *cnt) idxa[list[i]] = dec_idx(cell[i]);
}

// ---- scatter EMA stats (lane = channel -> coalesced atomics) -------------
__global__ __launch_bounds__(256) void k_scatter(const float* __restrict__ z_e,
                                                 const int* __restrict__ idxa,
                                                 float* __restrict__ out4,
                                                 float* __restrict__ out5) {
  int tid = blockIdx.x * 256 + threadIdx.x;   // 1M = 16384 tokens x 64 ch
  int n = tid >> 6, c = tid & 63;
  int idx = idxa[n];
  int b = n >> 10, hw = n & 1023;
  float x = z_e[((size_t)b << 16) + ((size_t)c << 10) + hw];
  atomicAdd(out5 + (size_t)idx * 64 + c, OMDF * x);
  if (c == 0) atomicAdd(out4 + idx, OMDF);
}

// ---- gather z_q / z_q_st / indices --------------------------------------
__global__ __launch_bounds__(256) void k_gather(const float* __restrict__ z_e,
                                                const float* __restrict__ emb,
                                                const int* __restrict__ idxa,
                                                float* __restrict__ out0,
                                                float* __restrict__ out1,
                                                float* __restrict__ out2) {
  int tid = blockIdx.x * 256 + threadIdx.x;   // 262144 = 16 b x 64 c x 256 hw4
  int hw4 = tid & 255;
  int c   = (tid >> 8) & 63;
  int b   = tid >> 14;
  int n0  = (b << 10) + (hw4 << 2);
  size_t off = ((size_t)b << 16) + ((size_t)c << 10) + ((size_t)hw4 << 2);
  float4 z = *(const float4*)(z_e + off);
  int i0 = idxa[n0], i1 = idxa[n0 + 1], i2 = idxa[n0 + 2], i3 = idxa[n0 + 3];
  float4 q;
  q.x = emb[(size_t)i0 * 64 + c];
  q.y = emb[(size_t)i1 * 64 + c];
  q.z = emb[(size_t)i2 * 64 + c];
  q.w = emb[(size_t)i3 * 64 + c];
  float4 st;
  st.x = z.x + (q.x - z.x);
  st.y = z.y + (q.y - z.y);
  st.z = z.z + (q.z - z.z);
  st.w = z.w + (q.w - z.w);
  *(float4*)(out2 + off) = q;
  *(float4*)(out0 + off) = st;
  if (c == 0) {
    float4 f = make_float4((float)i0, (float)i1, (float)i2, (float)i3);
    *(float4*)(out1 + n0) = f;
  }
}

// ---- new_embedding = new_embedding_avg / cs -----------------------------
__global__ __launch_bounds__(256) void k_final(const float* __restrict__ out4,
                                               const float* __restrict__ out5,
                                               const float* __restrict__ nsum,
                                               float* __restrict__ out3) {
  int tid = blockIdx.x * 256 + threadIdx.x;
  int k = tid >> 4;
  double nn  = (double)*nsum + 163.84;
  double ncs = (double)out4[k];
  double cs  = (ncs + 1e-5) / (nn + 8192.0 * 1e-5) * nn;
  float inv  = (float)(1.0 / cs);
  float4 v = ((const float4*)out5)[tid];
  v.x *= inv; v.y *= inv; v.z *= inv; v.w *= inv;
  ((float4*)out3)[tid] = v;
}

extern "C" void kernel_launch(void* const* d_in, const int* in_sizes, int n_in,
                              void* d_out, int out_size, void* d_ws, size_t ws_size,
                              hipStream_t stream) {
  const float* z_e    = (const float*)d_in[0];
  const float* emb    = (const float*)d_in[1];
  const float* cs_in  = (const float*)d_in[2];
  const float* avg_in = (const float*)d_in[3];

  float* out  = (float*)d_out;
  float* out0 = out;                    // z_q_st        1048576
  float* out1 = out0 + 1048576;         // indices(f32)  16384
  float* out2 = out1 + 16384;           // z_q           1048576
  float* out3 = out2 + 1048576;         // new_embedding 524288
  float* out4 = out3 + 524288;          // new_cluster   8192
  float* out5 = out4 + 8192;            // new_emb_avg   524288

  char* ws = (char*)d_ws;
  float* en            = (float*)(ws + EN_OFF);
  unsigned char* efrag = (unsigned char*)(ws + EFRAG_OFF);
  u64* best1           = (u64*)(ws + BEST1_OFF);
  float* best2         = (float*)(ws + BEST2_OFF);
  int* idxa            = (int*)(ws + IDX_OFF);
  int* list            = (int*)(ws + LIST_OFF);
  int* cnt             = (int*)(ws + CNT_OFF);
  float* nsum          = (float*)(ws + CNT_OFF + 4);
  u64* cell            = (u64*)(ws + CELL_OFF);

  k_en_eprep   <<<512,  256, 0, stream>>>(emb, en, efrag, cnt, nsum);
  k_init       <<<520,  256, 0, stream>>>(cs_in, avg_in, out4, out5, nsum);
  k_argmin_mfma<<<512,  256, 0, stream>>>(z_e, efrag, en, best1, best2);
  k_resolve    <<<64,   256, 0, stream>>>(best1, best2, idxa, list, cnt, cell);
  k_fixup      <<<2048, 256, 0, stream>>>(z_e, emb, en, list, cnt, cell);
  k_post       <<<64,   256, 0, stream>>>(list, cnt, cell, idxa);
  k_scatter    <<<4096, 256, 0, stream>>>(z_e, idxa, out4, out5);
  k_gather     <<<1024, 256, 0, stream>>>(z_e, emb, idxa, out0, out1, out2);
  k_final      <<<512,  256, 0, stream>>>(out4, out5, nsum, out3);
}